// Round 8
// baseline (553.933 us; speedup 1.0000x reference)
//
#include <hip/hip_runtime.h>
#include <math.h>

// Problem constants (B=1, H=4, N=2048, D=64, M=256)
#define NH   4
#define SEQ  2048
#define DH   64
#define NF   256
#define ROWS (NH*SEQ)                // 8192
#define DN    0.35355339059327373f   // 64^-0.25
#define DIAGC 0.0625f                // 0.5*DN*DN
#define RATIO 0.0625f                // 1/sqrt(256)
#define EPSF  1e-4f
#define NBLK 512

typedef __attribute__((ext_vector_type(8))) short bf8;
typedef __attribute__((ext_vector_type(4))) short bf4;
typedef __attribute__((ext_vector_type(4))) float f4;
typedef __attribute__((ext_vector_type(2))) unsigned int u32x2;

static __device__ __forceinline__ unsigned short f2bf(float x) {
  union { float f; unsigned u; } v; v.f = x;
  unsigned r = v.u + 0x7FFF + ((v.u >> 16) & 1);
  return (unsigned short)(r >> 16);
}
static __device__ __forceinline__ float bf2f(unsigned short b) {
  union { unsigned u; float f; } v; v.u = ((unsigned)b) << 16;
  return v.f;
}

// device-scope grid barrier: all NBLK blocks co-resident (launch_bounds(256,2))
static __device__ __forceinline__ void gbar(unsigned* c) {
  __syncthreads();
  __threadfence();                       // release: publish this block's writes
  if (threadIdx.x == 0) {
    atomicAdd(c, 1u);                    // device-scope by default
    while (__hip_atomic_load(c, __ATOMIC_ACQUIRE, __HIP_MEMORY_SCOPE_AGENT) < NBLK)
      __builtin_amdgcn_s_sleep(8);
  }
  __syncthreads();
  __threadfence();                       // acquire: invalidate stale cache lines
}

__global__ __launch_bounds__(256, 2) void mega(
    const float* __restrict__ q, const float* __restrict__ k,
    const float* __restrict__ v, const float* __restrict__ P,
    float* __restrict__ out,
    unsigned short* __restrict__ qfb, unsigned short* __restrict__ kfb,
    unsigned short* __restrict__ vtb, unsigned short* __restrict__ kft,
    float* __restrict__ dshd, float* __restrict__ bmax,
    float* __restrict__ csum, float* __restrict__ stateP,
    unsigned short* __restrict__ sthi, unsigned short* __restrict__ stlo,
    unsigned* __restrict__ ctr) {
  __shared__ __align__(16) char smem[16640];
  const int bid = blockIdx.x;
  const int tid = threadIdx.x;
  const int wid = tid >> 6, lane = tid & 63;
  const int lr = lane & 15, g = lane >> 4;

  // ================= Phase A: proj(q)->qfb, proj(k)->dshd+bmax, V^T =================
  for (int u = bid; u < 1152; u += NBLK) {
    __syncthreads();                     // protect smem reuse across units
    float* lds = (float*)smem;
    if (u >= 1024) {                     // ---- V transpose ----
      const int cb = u - 1024;
      const int h = cb >> 5, n0 = (cb & 31) * 64;
      for (int i = tid; i < 4096; i += 256) {
        int n = i >> 6, e = i & 63;
        lds[n*65 + e] = v[((size_t)h*SEQ + n0 + n)*DH + e];
      }
      __syncthreads();
      for (int i = tid; i < 4096; i += 256) {
        int e = i >> 6, n = i & 63;
        vtb[((size_t)h*DH + e)*SEQ + n0 + n] = f2bf(lds[n*65 + e]);
      }
      continue;
    }
    const bool isq = u < 512;
    const int tile = isq ? u : u - 512;  // h*128 + t
    const float* x = (isq ? q : k) + (size_t)tile*16*DH;

    f4 a  = *(const f4*)(x + lr*DH + g*8);
    f4 bb = *(const f4*)(x + lr*DH + g*8 + 4);
    f4 c  = *(const f4*)(x + lr*DH + 32 + g*8);
    f4 d  = *(const f4*)(x + lr*DH + 32 + g*8 + 4);
    float ss = 0.f;
#pragma unroll
    for (int i = 0; i < 4; ++i) ss += a[i]*a[i] + bb[i]*bb[i] + c[i]*c[i] + d[i]*d[i];
    ss += __shfl_xor(ss, 16);
    ss += __shfl_xor(ss, 32);            // full sum(x^2) of row lr

    bf8 xh0, xh1, xl0, xl1;
#pragma unroll
    for (int i = 0; i < 4; ++i) {
      float v0 = DN*a[i], v1 = DN*bb[i], v2 = DN*c[i], v3 = DN*d[i];
      unsigned short h0 = f2bf(v0), h1 = f2bf(v1), h2 = f2bf(v2), h3 = f2bf(v3);
      xh0[i] = (short)h0; xh0[i+4] = (short)h1;
      xh1[i] = (short)h2; xh1[i+4] = (short)h3;
      xl0[i]   = (short)f2bf(v0 - bf2f(h0)); xl0[i+4] = (short)f2bf(v1 - bf2f(h1));
      xl1[i]   = (short)f2bf(v2 - bf2f(h2)); xl1[i+4] = (short)f2bf(v3 - bf2f(h3));
    }

    const int ct0 = wid*4;
    f4 dsh[4];
#pragma unroll
    for (int cc = 0; cc < 4; ++cc) {
      const int ct = ct0 + cc;
      const float* prow = P + (ct*16 + lr)*DH + g*8;
      f4 p0 = *(const f4*)(prow);
      f4 p1 = *(const f4*)(prow + 4);
      f4 p2 = *(const f4*)(prow + 32);
      f4 p3 = *(const f4*)(prow + 36);
      bf8 bh0, bl0, bh1, bl1;
#pragma unroll
      for (int i = 0; i < 4; ++i) {
        unsigned short h0 = f2bf(p0[i]), h1 = f2bf(p1[i]);
        unsigned short h2 = f2bf(p2[i]), h3 = f2bf(p3[i]);
        bh0[i] = (short)h0; bh0[i+4] = (short)h1;
        bh1[i] = (short)h2; bh1[i+4] = (short)h3;
        bl0[i]   = (short)f2bf(p0[i] - bf2f(h0)); bl0[i+4] = (short)f2bf(p1[i] - bf2f(h1));
        bl1[i]   = (short)f2bf(p2[i] - bf2f(h2)); bl1[i+4] = (short)f2bf(p3[i] - bf2f(h3));
      }
      f4 acc = {0.f, 0.f, 0.f, 0.f};
      acc = __builtin_amdgcn_mfma_f32_16x16x32_bf16(xh0, bh0, acc, 0, 0, 0);
      acc = __builtin_amdgcn_mfma_f32_16x16x32_bf16(xh1, bh1, acc, 0, 0, 0);
      acc = __builtin_amdgcn_mfma_f32_16x16x32_bf16(xh0, bl0, acc, 0, 0, 0);
      acc = __builtin_amdgcn_mfma_f32_16x16x32_bf16(xh1, bl1, acc, 0, 0, 0);
      acc = __builtin_amdgcn_mfma_f32_16x16x32_bf16(xl0, bh0, acc, 0, 0, 0);
      acc = __builtin_amdgcn_mfma_f32_16x16x32_bf16(xl1, bh1, acc, 0, 0, 0);
      dsh[cc] = acc;
    }

    f4 mr;
#pragma unroll
    for (int r = 0; r < 4; ++r)
      mr[r] = fmaxf(fmaxf(dsh[0][r], dsh[1][r]), fmaxf(dsh[2][r], dsh[3][r]));
#pragma unroll
    for (int mk = 1; mk <= 8; mk <<= 1) {
#pragma unroll
      for (int r = 0; r < 4; ++r) mr[r] = fmaxf(mr[r], __shfl_xor(mr[r], mk));
    }
    if (lr == 0) {
#pragma unroll
      for (int r = 0; r < 4; ++r) lds[wid*16 + 4*g + r] = mr[r];
    }
    __syncthreads();
    float rm[4], sr[4];
#pragma unroll
    for (int r = 0; r < 4; ++r) {
      rm[r] = fmaxf(fmaxf(lds[0*16 + 4*g + r], lds[1*16 + 4*g + r]),
                    fmaxf(lds[2*16 + 4*g + r], lds[3*16 + 4*g + r]));
      sr[r] = __shfl(ss, 4*g + r);
    }

    if (isq) {
      unsigned short* ob = qfb + (size_t)tile*16*NF;
#pragma unroll
      for (int cc = 0; cc < 4; ++cc) {
#pragma unroll
        for (int r = 0; r < 4; ++r)
          ob[(4*g + r)*NF + (ct0 + cc)*16 + lr] =
              f2bf(RATIO*(expf(dsh[cc][r] - (sr[r]*DIAGC + rm[r])) + EPSF));
      }
    } else {
      float* db = dshd + (size_t)tile*16*NF;
#pragma unroll
      for (int cc = 0; cc < 4; ++cc) {
#pragma unroll
        for (int r = 0; r < 4; ++r)
          db[(4*g + r)*NF + (ct0 + cc)*16 + lr] = dsh[cc][r] - sr[r]*DIAGC;
      }
      if (wid == 0 && lr == 0) {
#pragma unroll
        for (int r = 0; r < 4; ++r) bmax[tile*16 + 4*g + r] = mr[r];
      }
    }
  }
  gbar(ctr + 0);

  // ================= Phase B: gmax + k_feat -> kfb, kft, csum =================
  for (int u = bid; u < 512; u += NBLK) {
    __syncthreads();
    float* red = (float*)smem;
    const int m = tid;
    const int h = u >> 7, t = u & 127;
    float mx = -3.4e38f;
    for (int i = m; i < ROWS; i += 256) mx = fmaxf(mx, bmax[i]);
    red[m] = mx;
    __syncthreads();
    for (int s = 128; s > 0; s >>= 1) {
      if (m < s) red[m] = fmaxf(red[m], red[m+s]);
      __syncthreads();
    }
    const float gg = red[0];
    const float* db = dshd + (size_t)u*16*NF + m;
    unsigned short* ob = kfb + (size_t)u*16*NF + m;
    float run = 0.f;
    bf8 k0, k1;
#pragma unroll
    for (int r = 0; r < 16; ++r) {
      unsigned short bv = f2bf(RATIO*(expf(db[r*NF] - gg) + EPSF));
      ob[r*NF] = bv;
      if (r < 8) k0[r] = (short)bv; else k1[r-8] = (short)bv;
      run += bf2f(bv);
    }
    csum[(size_t)u*NF + m] = run;
    unsigned short* kt = kft + ((size_t)(h*NF + m))*SEQ + t*16;
    *(bf8*)kt = k0;
    *(bf8*)(kt + 8) = k1;
  }
  gbar(ctr + 1);

  // ====== Phase C: state build (64 units) + in-place csum exclusive scan (4) ======
  for (int u = bid; u < 68; u += NBLK) {
    if (u < 64) {
      const int c = u & 15, h = u >> 4;
      f4 acc[4][4];
#pragma unroll
      for (int et = 0; et < 4; ++et)
#pragma unroll
        for (int mt = 0; mt < 4; ++mt) acc[et][mt] = (f4){0.f,0.f,0.f,0.f};
#pragma unroll
      for (int ks = 0; ks < 4; ++ks) {
        const int j0 = c*128 + ks*32 + g*8;
        bf8 xv[4], ym[4];
#pragma unroll
        for (int et = 0; et < 4; ++et)
          xv[et] = *(const bf8*)(vtb + ((size_t)(h*DH + et*16 + lr))*SEQ + j0);
#pragma unroll
        for (int mt = 0; mt < 4; ++mt)
          ym[mt] = *(const bf8*)(kft + ((size_t)(h*NF + (4*wid + mt)*16 + lr))*SEQ + j0);
#pragma unroll
        for (int et = 0; et < 4; ++et)
#pragma unroll
          for (int mt = 0; mt < 4; ++mt)
            acc[et][mt] = __builtin_amdgcn_mfma_f32_16x16x32_bf16(xv[et], ym[mt], acc[et][mt], 0, 0, 0);
      }
      float* sp = stateP + (size_t)(h*16 + c)*64*NF;
#pragma unroll
      for (int et = 0; et < 4; ++et)
#pragma unroll
        for (int mt = 0; mt < 4; ++mt)
#pragma unroll
          for (int r = 0; r < 4; ++r)
            sp[(size_t)(et*16 + 4*g + r)*NF + (4*wid + mt)*16 + lr] = acc[et][mt][r];
    } else {
      const int h = u - 64;                 // csum scan for head h (exclusive)
      float* cs = csum + (size_t)(h*128)*NF + tid;
      float run = 0.f;
      for (int c = 0; c < 128; ++c) {
        float x = cs[(size_t)c*NF];
        cs[(size_t)c*NF] = run;
        run += x;
      }
    }
  }
  gbar(ctr + 2);

  // ====== Phase D: state exclusive cumsum -> hi/lo (64) + q' divide (512) ======
  for (int u = bid; u < 576; u += NBLK) {
    if (u < 64) {
      const int eg = u & 15, h = u >> 4;
      const int er = tid >> 6, m0 = (tid & 63)*4;
      const int e = eg*4 + er;
      f4 run = {0.f, 0.f, 0.f, 0.f};
      for (int c = 0; c < 16; ++c) {
        const size_t idx = (size_t)((h*16 + c)*64 + e)*NF + m0;
        unsigned short hi[4], lo[4];
#pragma unroll
        for (int i = 0; i < 4; ++i) {
          hi[i] = f2bf(run[i]);
          lo[i] = f2bf(run[i] - bf2f(hi[i]));
        }
        *(bf4*)(sthi + idx) = *(bf4*)hi;
        *(bf4*)(stlo + idx) = *(bf4*)lo;
        run += *(const f4*)(stateP + idx);
      }
    } else {
      const int up = u - 64, m = tid;       // tile u': csum already exclusive
      float run = csum[(size_t)up*NF + m];
#pragma unroll
      for (int r = 0; r < 16; ++r) {
        size_t idx = (size_t)(up*16 + r)*NF + m;
        run += bf2f(kfb[idx]);
        qfb[idx] = f2bf(bf2f(qfb[idx]) / run);
      }
    }
  }
  gbar(ctr + 3);

  // ================= Phase E: chunked causal attention (128 units) =================
  for (int u = bid; u < 128; u += NBLK) {
    const int h = u >> 5;
    const int b = u & 31;
    const int c = b >> 1, half = b & 1;
    const int t = c*8 + half*4 + wid;
    const int jc0 = c*8;
    const int nstage = half*4 + 4;

    unsigned short* Ks = (unsigned short*)smem;          // 8KB, XOR-swizzled
    unsigned short* Vs = (unsigned short*)(smem + 8192); // 2KB

    const unsigned short* qb = qfb + ((size_t)(h*SEQ + t*16 + lr))*NF + g*8;
    bf8 qf[8];
#pragma unroll
    for (int kb = 0; kb < 8; ++kb) qf[kb] = *(const bf8*)(qb + kb*32);

    const char* kTile = (const char*)(kfb + (size_t)h*SEQ*NF);
    const char* vTile = (const char*)(vtb + (size_t)h*DH*SEQ);

    const int ko0 = (wid*2 + 0)*1024 + lane*16;
    const int ko1 = (wid*2 + 1)*1024 + lane*16;
    const int kw0 = ko0 ^ (((ko0 >> 9) & 7) << 4);
    const int kw1 = ko1 ^ (((ko1 >> 9) & 7) << 4);
    const int vo = wid*512 + lane*8;
    const int ve = vo >> 5;
    const int vn = vo & 31;

    f4 sk0, sk1; u32x2 sv;
    {
      const char* kt = kTile + (size_t)jc0*8192;
      sk0 = *(const f4*)(kt + ko0);
      sk1 = *(const f4*)(kt + ko1);
      sv  = *(const u32x2*)(vTile + (size_t)ve*4096 + (size_t)jc0*32 + vn);
    }

    // inter-chunk: O = q' x cumstate (hi/lo)
    f4 o0 = {0,0,0,0}, o1 = {0,0,0,0}, o2 = {0,0,0,0}, o3 = {0,0,0,0};
    {
      const unsigned short* SH = sthi + ((size_t)((h*16 + c)*64 + lr))*NF + g*8;
      const unsigned short* SL = stlo + ((size_t)((h*16 + c)*64 + lr))*NF + g*8;
#pragma unroll
      for (int ks = 0; ks < 8; ++ks) {
#pragma unroll
        for (int et = 0; et < 4; ++et) {
          bf8 bh = *(const bf8*)(SH + et*16*NF + ks*32);
          bf8 bl = *(const bf8*)(SL + et*16*NF + ks*32);
          f4 acc = (et == 0) ? o0 : (et == 1) ? o1 : (et == 2) ? o2 : o3;
          acc = __builtin_amdgcn_mfma_f32_16x16x32_bf16(qf[ks], bh, acc, 0, 0, 0);
          acc = __builtin_amdgcn_mfma_f32_16x16x32_bf16(qf[ks], bl, acc, 0, 0, 0);
          if (et == 0) o0 = acc; else if (et == 1) o1 = acc; else if (et == 2) o2 = acc; else o3 = acc;
        }
      }
    }

    // intra-chunk causal sweep
    for (int jj = 0; jj < nstage; ++jj) {
      const int j = jc0 + jj;
      *(f4*)((char*)Ks + kw0) = sk0;
      *(f4*)((char*)Ks + kw1) = sk1;
      *(u32x2*)((char*)Vs + vo) = sv;
      __syncthreads();
      if (jj + 1 < nstage) {
        const char* kt = kTile + (size_t)(j+1)*8192;
        sk0 = *(const f4*)(kt + ko0);
        sk1 = *(const f4*)(kt + ko1);
        sv  = *(const u32x2*)(vTile + (size_t)ve*4096 + (size_t)(j+1)*32 + vn);
      }
      if (j <= t) {
        bf8 kcs[8];
#pragma unroll
        for (int kb = 0; kb < 8; ++kb) {
          int off = (lr*512 + kb*64 + g*16) ^ ((lr & 7) << 4);
          kcs[kb] = *(const bf8*)((const char*)Ks + off);
        }
        f4 st = {0,0,0,0};
#pragma unroll
        for (int kb = 0; kb < 8; ++kb)
          st = __builtin_amdgcn_mfma_f32_16x16x32_bf16(kcs[kb], qf[kb], st, 0, 0, 0);
        if (j == t) {
#pragma unroll
          for (int rr = 0; rr < 4; ++rr) if (g*4 + rr > lr) st[rr] = 0.f;
        }
        bf8 sb = { (short)f2bf(st[0]), (short)f2bf(st[1]), (short)f2bf(st[2]), (short)f2bf(st[3]),
                   (short)0, (short)0, (short)0, (short)0 };
#pragma unroll
        for (int eb = 0; eb < 4; ++eb) {
          bf4 v4 = *(const bf4*)((const char*)Vs + (eb*16 + lr)*32 + g*8);
          bf8 vf = { v4[0], v4[1], v4[2], v4[3], (short)0, (short)0, (short)0, (short)0 };
          f4 acc = (eb == 0) ? o0 : (eb == 1) ? o1 : (eb == 2) ? o2 : o3;
          acc = __builtin_amdgcn_mfma_f32_16x16x32_bf16(sb, vf, acc, 0, 0, 0);
          if (eb == 0) o0 = acc; else if (eb == 1) o1 = acc; else if (eb == 2) o2 = acc; else o3 = acc;
        }
      }
      __syncthreads();
    }

    float* ob = out + ((size_t)(h*SEQ + t*16))*DH;
#pragma unroll
    for (int rr = 0; rr < 4; ++rr) {
      ob[(size_t)(4*g + rr)*DH +  0 + lr] = o0[rr];
      ob[(size_t)(4*g + rr)*DH + 16 + lr] = o1[rr];
      ob[(size_t)(4*g + rr)*DH + 32 + lr] = o2[rr];
      ob[(size_t)(4*g + rr)*DH + 48 + lr] = o3[rr];
    }
  }
}

extern "C" void kernel_launch(void* const* d_in, const int* in_sizes, int n_in,
                              void* d_out, int out_size, void* d_ws, size_t ws_size,
                              hipStream_t stream) {
  const float* q = (const float*)d_in[0];
  const float* k = (const float*)d_in[1];
  const float* v = (const float*)d_in[2];
  const float* P = (const float*)d_in[3];
  float* out = (float*)d_out;

  char* ws = (char*)d_ws;                                    // 256 MiB available
  unsigned short* qfb  = (unsigned short*)(ws);              // 4 MB
  unsigned short* kfb  = (unsigned short*)(ws + (4u<<20));   // 4 MB
  unsigned short* vtb  = (unsigned short*)(ws + (8u<<20));   // 1 MB
  unsigned short* kft  = (unsigned short*)(ws + (12u<<20));  // 4 MB (m-major kf)
  float* dshd   = (float*)(ws + (16u<<20));                  // 8 MB
  float* bmax   = (float*)(ws + (24u<<20));                  // 32 KB
  float* csum   = (float*)(ws + (25u<<20));                  // 512 KB
  float* stateP = (float*)(ws + (28u<<20));                  // 4 MB
  unsigned short* sthi = (unsigned short*)(ws + (33u<<20));  // 2 MB
  unsigned short* stlo = (unsigned short*)(ws + (36u<<20));  // 2 MB
  unsigned* ctr = (unsigned*)(ws + (48u<<20));               // 4 barrier counters

  hipMemsetAsync(ctr, 0, 64, stream);
  mega<<<NBLK, 256, 0, stream>>>(q, k, v, P, out, qfb, kfb, vtb, kft,
                                 dshd, bmax, csum, stateP, sthi, stlo, ctr);
}

// Round 9
// 69.979 us; speedup vs baseline: 7.9157x; 7.9157x over previous
//
#include <hip/hip_runtime.h>
#include <math.h>

// Problem constants (B=1, H=4, N=2048, D=64, M=256)
#define NH   4
#define SEQ  2048
#define DH   64
#define NF   256
#define ROWS (NH*SEQ)                // 8192
#define DN    0.35355339059327373f   // 64^-0.25
#define DIAGC 0.0625f                // 0.5*DN*DN
#define RATIO 0.0625f                // 1/sqrt(256)
#define EPSF  1e-4f

typedef __attribute__((ext_vector_type(8))) short bf8;
typedef __attribute__((ext_vector_type(4))) short bf4;
typedef __attribute__((ext_vector_type(4))) float f4;
typedef __attribute__((ext_vector_type(2))) unsigned int u32x2;

static __device__ __forceinline__ unsigned short f2bf(float x) {
  union { float f; unsigned u; } v; v.f = x;
  unsigned r = v.u + 0x7FFF + ((v.u >> 16) & 1);
  return (unsigned short)(r >> 16);
}
static __device__ __forceinline__ float bf2f(unsigned short b) {
  union { unsigned u; float f; } v; v.u = ((unsigned)b) << 16;
  return v.f;
}

// ---- fused projection (q: full features; k: dsh-diag fp32 + rowmax) + V^T ----
// blocks 0..511: q tiles; 512..1023: k tiles; 1024..1151: V transpose.
__global__ __launch_bounds__(256) void k_proj(const float* __restrict__ q,
    const float* __restrict__ k, const float* __restrict__ v,
    const float* __restrict__ P,
    unsigned short* __restrict__ qfb, float* __restrict__ dshd,
    float* __restrict__ bmax, unsigned short* __restrict__ vtb) {
  __shared__ float lds[64*65];
  const int b = blockIdx.x;
  if (b >= 1024) {                       // ---- V transpose: 128 blocks ----
    const int cb = b - 1024;
    const int h = cb >> 5, n0 = (cb & 31) * 64;
    const int tid = threadIdx.x;
    for (int i = tid; i < 4096; i += 256) {
      int n = i >> 6, e = i & 63;
      lds[n*65 + e] = v[((size_t)h*SEQ + n0 + n)*DH + e];
    }
    __syncthreads();
    for (int i = tid; i < 4096; i += 256) {
      int e = i >> 6, n = i & 63;
      vtb[((size_t)h*DH + e)*SEQ + n0 + n] = f2bf(lds[n*65 + e]);
    }
    return;
  }
  const bool isq = b < 512;
  const int tile = isq ? b : b - 512;    // h*128 + t
  const int w = threadIdx.x >> 6, lane = threadIdx.x & 63;
  const int lr = lane & 15, g = lane >> 4;
  const float* x = (isq ? q : k) + (size_t)tile*16*DH;

  f4 a  = *(const f4*)(x + lr*DH + g*8);
  f4 bb = *(const f4*)(x + lr*DH + g*8 + 4);
  f4 c  = *(const f4*)(x + lr*DH + 32 + g*8);
  f4 d  = *(const f4*)(x + lr*DH + 32 + g*8 + 4);
  float ss = 0.f;
#pragma unroll
  for (int i = 0; i < 4; ++i) ss += a[i]*a[i] + bb[i]*bb[i] + c[i]*c[i] + d[i]*d[i];
  ss += __shfl_xor(ss, 16);
  ss += __shfl_xor(ss, 32);              // full sum(x^2) of row lr

  bf8 xh0, xh1, xl0, xl1;
#pragma unroll
  for (int i = 0; i < 4; ++i) {
    float v0 = DN*a[i], v1 = DN*bb[i], v2 = DN*c[i], v3 = DN*d[i];
    unsigned short h0 = f2bf(v0), h1 = f2bf(v1), h2 = f2bf(v2), h3 = f2bf(v3);
    xh0[i] = (short)h0; xh0[i+4] = (short)h1;
    xh1[i] = (short)h2; xh1[i+4] = (short)h3;
    xl0[i]   = (short)f2bf(v0 - bf2f(h0)); xl0[i+4] = (short)f2bf(v1 - bf2f(h1));
    xl1[i]   = (short)f2bf(v2 - bf2f(h2)); xl1[i+4] = (short)f2bf(v3 - bf2f(h3));
  }

  const int ct0 = w*4;
  f4 dsh[4];
#pragma unroll
  for (int cc = 0; cc < 4; ++cc) {
    const int ct = ct0 + cc;
    const float* prow = P + (ct*16 + lr)*DH + g*8;
    f4 p0 = *(const f4*)(prow);
    f4 p1 = *(const f4*)(prow + 4);
    f4 p2 = *(const f4*)(prow + 32);
    f4 p3 = *(const f4*)(prow + 36);
    bf8 bh0, bl0, bh1, bl1;
#pragma unroll
    for (int i = 0; i < 4; ++i) {
      unsigned short h0 = f2bf(p0[i]), h1 = f2bf(p1[i]);
      unsigned short h2 = f2bf(p2[i]), h3 = f2bf(p3[i]);
      bh0[i] = (short)h0; bh0[i+4] = (short)h1;
      bh1[i] = (short)h2; bh1[i+4] = (short)h3;
      bl0[i]   = (short)f2bf(p0[i] - bf2f(h0)); bl0[i+4] = (short)f2bf(p1[i] - bf2f(h1));
      bl1[i]   = (short)f2bf(p2[i] - bf2f(h2)); bl1[i+4] = (short)f2bf(p3[i] - bf2f(h3));
    }
    f4 acc = {0.f, 0.f, 0.f, 0.f};
    acc = __builtin_amdgcn_mfma_f32_16x16x32_bf16(xh0, bh0, acc, 0, 0, 0);
    acc = __builtin_amdgcn_mfma_f32_16x16x32_bf16(xh1, bh1, acc, 0, 0, 0);
    acc = __builtin_amdgcn_mfma_f32_16x16x32_bf16(xh0, bl0, acc, 0, 0, 0);
    acc = __builtin_amdgcn_mfma_f32_16x16x32_bf16(xh1, bl1, acc, 0, 0, 0);
    acc = __builtin_amdgcn_mfma_f32_16x16x32_bf16(xl0, bh0, acc, 0, 0, 0);
    acc = __builtin_amdgcn_mfma_f32_16x16x32_bf16(xl1, bh1, acc, 0, 0, 0);
    dsh[cc] = acc;
  }

  f4 mr;
#pragma unroll
  for (int r = 0; r < 4; ++r)
    mr[r] = fmaxf(fmaxf(dsh[0][r], dsh[1][r]), fmaxf(dsh[2][r], dsh[3][r]));
#pragma unroll
  for (int mk = 1; mk <= 8; mk <<= 1) {
#pragma unroll
    for (int r = 0; r < 4; ++r) mr[r] = fmaxf(mr[r], __shfl_xor(mr[r], mk));
  }
  if (lr == 0) {
#pragma unroll
    for (int r = 0; r < 4; ++r) lds[w*16 + 4*g + r] = mr[r];
  }
  __syncthreads();
  float rm[4], sr[4];
#pragma unroll
  for (int r = 0; r < 4; ++r) {
    rm[r] = fmaxf(fmaxf(lds[0*16 + 4*g + r], lds[1*16 + 4*g + r]),
                  fmaxf(lds[2*16 + 4*g + r], lds[3*16 + 4*g + r]));
    sr[r] = __shfl(ss, 4*g + r);
  }

  if (isq) {
    unsigned short* ob = qfb + (size_t)tile*16*NF;
#pragma unroll
    for (int cc = 0; cc < 4; ++cc) {
#pragma unroll
      for (int r = 0; r < 4; ++r)
        ob[(4*g + r)*NF + (ct0 + cc)*16 + lr] =
            f2bf(RATIO*(expf(dsh[cc][r] - (sr[r]*DIAGC + rm[r])) + EPSF));
    }
  } else {
    float* db = dshd + (size_t)tile*16*NF;
#pragma unroll
    for (int cc = 0; cc < 4; ++cc) {
#pragma unroll
      for (int r = 0; r < 4; ++r)
        db[(4*g + r)*NF + (ct0 + cc)*16 + lr] = dsh[cc][r] - sr[r]*DIAGC;
    }
    if (w == 0 && lr == 0) {
#pragma unroll
      for (int r = 0; r < 4; ++r) bmax[tile*16 + 4*g + r] = mr[r];
    }
  }
}

// ---- k_feat: gmax (inline) + exp -> kfb bf16 + kft (m-major) + tile sums ----
__global__ __launch_bounds__(256) void k_feat2(const float* __restrict__ dshd,
    const float* __restrict__ bmax, unsigned short* __restrict__ kfb,
    unsigned short* __restrict__ kft, float* __restrict__ csum) {
  const int u = blockIdx.x, m = threadIdx.x;     // u: 0..511 = h*128 + t
  const int h = u >> 7, t = u & 127;
  __shared__ float red[256];
  float mx = -3.4e38f;
  for (int i = m; i < ROWS; i += 256) mx = fmaxf(mx, bmax[i]);
  red[m] = mx;
  __syncthreads();
  for (int s = 128; s > 0; s >>= 1) {
    if (m < s) red[m] = fmaxf(red[m], red[m+s]);
    __syncthreads();
  }
  const float gg = red[0];
  const float* db = dshd + (size_t)u*16*NF + m;
  unsigned short* ob = kfb + (size_t)u*16*NF + m;
  float run = 0.f;
  bf8 k0, k1;
#pragma unroll
  for (int r = 0; r < 16; ++r) {
    unsigned short bv = f2bf(RATIO*(expf(db[r*NF] - gg) + EPSF));
    ob[r*NF] = bv;
    if (r < 8) k0[r] = (short)bv; else k1[r-8] = (short)bv;
    run += bf2f(bv);
  }
  csum[(size_t)u*NF + m] = run;
  unsigned short* kt = kft + ((size_t)(h*NF + m))*SEQ + t*16;
  *(bf8*)kt = k0;
  *(bf8*)(kt + 8) = k1;
}

// ---- fused state build + exclusive cumsum -> hi/lo bf16 ----
// wave-unit = (h, et, mt): one 16(e)x16(m) tile, walks 16 chunks.
__global__ __launch_bounds__(256) void k_state(
    const unsigned short* __restrict__ vtb, const unsigned short* __restrict__ kft,
    unsigned short* __restrict__ sthi, unsigned short* __restrict__ stlo) {
  const int wid = threadIdx.x >> 6, lane = threadIdx.x & 63;
  const int lr = lane & 15, g = lane >> 4;
  const int unit = blockIdx.x*4 + wid;       // 0..255
  const int h = unit >> 6, et = (unit >> 4) & 3, mt = unit & 15;

  const unsigned short* vb = vtb + ((size_t)(h*DH + et*16 + lr))*SEQ;
  const unsigned short* kb = kft + ((size_t)(h*NF + mt*16 + lr))*SEQ;

  f4 cum = {0.f, 0.f, 0.f, 0.f};
  for (int c = 0; c < 16; ++c) {
    // write EXCLUSIVE cumulative state (hi/lo) for chunk c
    const size_t base = ((size_t)((h*16 + c)*64 + et*16 + 4*g))*NF + mt*16 + lr;
#pragma unroll
    for (int r = 0; r < 4; ++r) {
      unsigned short hi = f2bf(cum[r]);
      sthi[base + (size_t)r*NF] = hi;
      stlo[base + (size_t)r*NF] = f2bf(cum[r] - bf2f(hi));
    }
    // accumulate chunk c into cum
#pragma unroll
    for (int ks = 0; ks < 4; ++ks) {
      const int j0 = c*128 + ks*32 + g*8;
      bf8 xv = *(const bf8*)(vb + j0);
      bf8 ym = *(const bf8*)(kb + j0);
      cum = __builtin_amdgcn_mfma_f32_16x16x32_bf16(xv, ym, cum, 0, 0, 0);
    }
  }
}

// ---- chunked causal attention with fused q'-divide prologue ----
// block = (h, chunk, half): 32 blocks/head; 4 waves = 4 row-tiles.
__global__ __launch_bounds__(256) void k_attn3(const unsigned short* __restrict__ qfb,
                                               const unsigned short* __restrict__ kfb,
                                               const unsigned short* __restrict__ vtb,
                                               const unsigned short* __restrict__ sthi,
                                               const unsigned short* __restrict__ stlo,
                                               const float* __restrict__ csum,
                                               float* __restrict__ out) {
  const int h = blockIdx.y;
  const int b = blockIdx.x;            // 0..31
  const int c = b >> 1, half = b & 1;  // chunk 0..15
  const int wid = threadIdx.x >> 6, lane = threadIdx.x & 63;
  const int lr = lane & 15, g = lane >> 4;
  const int row0 = c*128 + half*64;    // this block's 64 contiguous rows
  const int tile0 = c*8 + half*4;
  const int t = tile0 + wid;           // this wave's row-tile
  const int jc0 = c*8;
  const int nstage = half*4 + 4;

  __shared__ __align__(16) char smem[43008];
  unsigned short* Ks = (unsigned short*)(smem + 32768);  // 8KB, XOR-swizzled
  unsigned short* Vs = (unsigned short*)(smem + 40960);  // 2KB
  // Qs: bytes [0,32768): 64 rows x 256 m bf16, XOR-swizzled

  // ---- prime prologue: q' = q_feat / cumsum(k_feat) for rows [row0,row0+64) ----
  {
    const int m = threadIdx.x;
    const float* cs = csum + (size_t)(h*128)*NF + m;
    float run = 0.f;
#pragma unroll 8
    for (int c2 = 0; c2 < tile0; ++c2) run += cs[(size_t)c2*NF];
    const unsigned short* kfp = kfb + ((size_t)(h*SEQ + row0))*NF + m;
    const unsigned short* qfp = qfb + ((size_t)(h*SEQ + row0))*NF + m;
#pragma unroll 8
    for (int r = 0; r < 64; ++r) {
      run += bf2f(kfp[(size_t)r*NF]);
      float qv = bf2f(qfp[(size_t)r*NF]) / run;
      const int byte = (r*512 + m*2) ^ ((r & 7) << 4);
      *(unsigned short*)(smem + byte) = f2bf(qv);
    }
  }
  __syncthreads();

  // Q' A-fragments from swizzled LDS
  bf8 qf[8];
  {
    const int rloc = wid*16 + lr;
#pragma unroll
    for (int kb = 0; kb < 8; ++kb) {
      const int byte = (rloc*512 + g*16 + kb*64) ^ ((rloc & 7) << 4);
      qf[kb] = *(const bf8*)(smem + byte);
    }
  }

  const char* kTile = (const char*)(kfb + (size_t)h*SEQ*NF);
  const char* vTile = (const char*)(vtb + (size_t)h*DH*SEQ);

  const int ko0 = (wid*2 + 0)*1024 + lane*16;
  const int ko1 = (wid*2 + 1)*1024 + lane*16;
  const int kw0 = ko0 ^ (((ko0 >> 9) & 7) << 4);
  const int kw1 = ko1 ^ (((ko1 >> 9) & 7) << 4);
  const int vo = wid*512 + lane*8;
  const int ve = vo >> 5;
  const int vn = vo & 31;

  f4 sk0, sk1; u32x2 sv;
  {  // prologue: issue staging loads for first j-tile (fly under inter-GEMM)
    const char* kt = kTile + (size_t)jc0*8192;
    sk0 = *(const f4*)(kt + ko0);
    sk1 = *(const f4*)(kt + ko1);
    sv  = *(const u32x2*)(vTile + (size_t)ve*4096 + (size_t)jc0*32 + vn);
  }

  // ---- inter-chunk: O = q' x cumstate (hi/lo split) ----
  f4 o0 = {0,0,0,0}, o1 = {0,0,0,0}, o2 = {0,0,0,0}, o3 = {0,0,0,0};
  {
    const unsigned short* SH = sthi + ((size_t)((h*16 + c)*64 + lr))*NF + g*8;
    const unsigned short* SL = stlo + ((size_t)((h*16 + c)*64 + lr))*NF + g*8;
#pragma unroll
    for (int ks = 0; ks < 8; ++ks) {
#pragma unroll
      for (int et = 0; et < 4; ++et) {
        bf8 bh = *(const bf8*)(SH + et*16*NF + ks*32);
        bf8 bl = *(const bf8*)(SL + et*16*NF + ks*32);
        f4 acc = (et == 0) ? o0 : (et == 1) ? o1 : (et == 2) ? o2 : o3;
        acc = __builtin_amdgcn_mfma_f32_16x16x32_bf16(qf[ks], bh, acc, 0, 0, 0);
        acc = __builtin_amdgcn_mfma_f32_16x16x32_bf16(qf[ks], bl, acc, 0, 0, 0);
        if (et == 0) o0 = acc; else if (et == 1) o1 = acc; else if (et == 2) o2 = acc; else o3 = acc;
      }
    }
  }

  // ---- intra-chunk causal sweep over staged K/V tiles ----
  for (int jj = 0; jj < nstage; ++jj) {
    const int j = jc0 + jj;
    *(f4*)((char*)Ks + kw0) = sk0;
    *(f4*)((char*)Ks + kw1) = sk1;
    *(u32x2*)((char*)Vs + vo) = sv;
    __syncthreads();
    if (jj + 1 < nstage) {
      const char* kt = kTile + (size_t)(j+1)*8192;
      sk0 = *(const f4*)(kt + ko0);
      sk1 = *(const f4*)(kt + ko1);
      sv  = *(const u32x2*)(vTile + (size_t)ve*4096 + (size_t)(j+1)*32 + vn);
    }
    if (j <= t) {
      bf8 kcs[8];
#pragma unroll
      for (int kb = 0; kb < 8; ++kb) {
        int off = (lr*512 + kb*64 + g*16) ^ ((lr & 7) << 4);
        kcs[kb] = *(const bf8*)((const char*)Ks + off);
      }
      f4 st = {0,0,0,0};
#pragma unroll
      for (int kb = 0; kb < 8; ++kb)
        st = __builtin_amdgcn_mfma_f32_16x16x32_bf16(kcs[kb], qf[kb], st, 0, 0, 0);
      if (j == t) {
#pragma unroll
        for (int rr = 0; rr < 4; ++rr) if (g*4 + rr > lr) st[rr] = 0.f;
      }
      bf8 sb = { (short)f2bf(st[0]), (short)f2bf(st[1]), (short)f2bf(st[2]), (short)f2bf(st[3]),
                 (short)0, (short)0, (short)0, (short)0 };
#pragma unroll
      for (int eb = 0; eb < 4; ++eb) {
        bf4 v4 = *(const bf4*)((const char*)Vs + (eb*16 + lr)*32 + g*8);
        bf8 vf = { v4[0], v4[1], v4[2], v4[3], (short)0, (short)0, (short)0, (short)0 };
        f4 acc = (eb == 0) ? o0 : (eb == 1) ? o1 : (eb == 2) ? o2 : o3;
        acc = __builtin_amdgcn_mfma_f32_16x16x32_bf16(sb, vf, acc, 0, 0, 0);
        if (eb == 0) o0 = acc; else if (eb == 1) o1 = acc; else if (eb == 2) o2 = acc; else o3 = acc;
      }
    }
    __syncthreads();
  }

  float* ob = out + ((size_t)(h*SEQ + t*16))*DH;
#pragma unroll
  for (int rr = 0; rr < 4; ++rr) {
    ob[(size_t)(4*g + rr)*DH +  0 + lr] = o0[rr];
    ob[(size_t)(4*g + rr)*DH + 16 + lr] = o1[rr];
    ob[(size_t)(4*g + rr)*DH + 32 + lr] = o2[rr];
    ob[(size_t)(4*g + rr)*DH + 48 + lr] = o3[rr];
  }
}

extern "C" void kernel_launch(void* const* d_in, const int* in_sizes, int n_in,
                              void* d_out, int out_size, void* d_ws, size_t ws_size,
                              hipStream_t stream) {
  const float* q = (const float*)d_in[0];
  const float* k = (const float*)d_in[1];
  const float* v = (const float*)d_in[2];
  const float* P = (const float*)d_in[3];
  float* out = (float*)d_out;

  char* ws = (char*)d_ws;                                    // 256 MiB available
  unsigned short* qfb  = (unsigned short*)(ws);              // 4 MB
  unsigned short* kfb  = (unsigned short*)(ws + (4u<<20));   // 4 MB
  unsigned short* vtb  = (unsigned short*)(ws + (8u<<20));   // 1 MB
  unsigned short* kft  = (unsigned short*)(ws + (12u<<20));  // 4 MB (m-major kf)
  float* dshd   = (float*)(ws + (16u<<20));                  // 8 MB
  float* bmax   = (float*)(ws + (24u<<20));                  // 32 KB
  float* csum   = (float*)(ws + (25u<<20));                  // 512 KB
  unsigned short* sthi = (unsigned short*)(ws + (33u<<20));  // 2 MB
  unsigned short* stlo = (unsigned short*)(ws + (36u<<20));  // 2 MB

  k_proj  <<<1152, 256, 0, stream>>>(q, k, v, P, qfb, dshd, bmax, vtb);
  k_feat2 <<<512, 256, 0, stream>>>(dshd, bmax, kfb, kft, csum);
  k_state <<<64, 256, 0, stream>>>(vtb, kft, sthi, stlo);
  k_attn3 <<<dim3(32, NH), 256, 0, stream>>>(qfb, kfb, vtb, sthi, stlo, csum, out);
}